// Round 1
// baseline (814.404 us; speedup 1.0000x reference)
//
#include <hip/hip_runtime.h>

#define N_NODES 50000
#define N_EDGES 800000
#define H 64

__device__ __forceinline__ float readlane_f(float x, int i) {
    return __int_as_float(__builtin_amdgcn_readlane(__float_as_int(x), i));
}

// Stage 1: scatter-add edge features into per-node sums (in d_out) + counts (in d_ws).
// One thread per (edge, float4-chunk): 16 chunks of 16B per 64-float edge row.
__global__ __launch_bounds__(256) void scatter_kernel(
    const float* __restrict__ e, const int* __restrict__ recv,
    float* __restrict__ sums, float* __restrict__ counts)
{
    int tid = blockIdx.x * 256 + threadIdx.x;
    int edge = tid >> 4;
    if (edge >= N_EDGES) return;
    int c = tid & 15;
    int r = recv[edge];
    float4 val = reinterpret_cast<const float4*>(e)[edge * 16 + c];
    float* dst = sums + (size_t)r * H + c * 4;
    atomicAdd(dst + 0, val.x);
    atomicAdd(dst + 1, val.y);
    atomicAdd(dst + 2, val.z);
    atomicAdd(dst + 3, val.w);
    if (c == 0) atomicAdd(counts + r, 1.0f);
}

// Stage 2: per-node MLP. One wave handles 4 nodes; lane j owns output feature j.
// x values live in registers; broadcast via v_readlane (uniform SGPR loop index),
// weight rows come from LDS (one ds_read_b32 per K-step, shared by 4 nodes).
__global__ __launch_bounds__(256) void mlp_kernel(
    const float* __restrict__ v, const float* __restrict__ counts,
    const float* __restrict__ W0, const float* __restrict__ b0,
    const float* __restrict__ W1, const float* __restrict__ b1,
    const float* __restrict__ W2, const float* __restrict__ b2,
    float* __restrict__ out)   // in: sums, out: final result (in-place per node row)
{
    __shared__ float sW0[128 * 64];
    __shared__ float sW1[64 * 64];
    __shared__ float sW2[64 * 64];
    __shared__ float sB[3 * 64];

    for (int i = threadIdx.x; i < 128 * 64; i += 256) sW0[i] = W0[i];
    for (int i = threadIdx.x; i < 64 * 64; i += 256) sW1[i] = W1[i];
    for (int i = threadIdx.x; i < 64 * 64; i += 256) sW2[i] = W2[i];
    if (threadIdx.x < 64) {
        sB[threadIdx.x]       = b0[threadIdx.x];
        sB[64 + threadIdx.x]  = b1[threadIdx.x];
        sB[128 + threadIdx.x] = b2[threadIdx.x];
    }
    __syncthreads();

    const int lane = threadIdx.x & 63;
    const int wave = (blockIdx.x * 256 + threadIdx.x) >> 6;
    const int nodeBase = wave * 4;              // 12500 waves * 4 = 50000 exactly
    if (nodeBase >= N_NODES) return;

    float xa[4], xv[4];
    #pragma unroll
    for (int k = 0; k < 4; ++k) {
        int n = nodeBase + k;
        float cnt = counts[n];
        float inv = 1.0f / fmaxf(cnt, 1.0f);
        xa[k] = out[n * 64 + lane] * inv;       // agg = sums / max(count,1)
        xv[k] = v[n * 64 + lane];
    }

    float acc[4];
    #pragma unroll
    for (int k = 0; k < 4; ++k) acc[k] = sB[lane];
    // layer 0: x = [agg, v] (128), W0 row-major [128][64]
    #pragma unroll 8
    for (int i = 0; i < 64; ++i) {
        float w = sW0[i * 64 + lane];
        #pragma unroll
        for (int k = 0; k < 4; ++k) acc[k] = fmaf(readlane_f(xa[k], i), w, acc[k]);
    }
    #pragma unroll 8
    for (int i = 0; i < 64; ++i) {
        float w = sW0[(64 + i) * 64 + lane];
        #pragma unroll
        for (int k = 0; k < 4; ++k) acc[k] = fmaf(readlane_f(xv[k], i), w, acc[k]);
    }
    float y[4];
    #pragma unroll
    for (int k = 0; k < 4; ++k) y[k] = fmaxf(acc[k], 0.0f);

    #pragma unroll
    for (int k = 0; k < 4; ++k) acc[k] = sB[64 + lane];
    #pragma unroll 8
    for (int i = 0; i < 64; ++i) {
        float w = sW1[i * 64 + lane];
        #pragma unroll
        for (int k = 0; k < 4; ++k) acc[k] = fmaf(readlane_f(y[k], i), w, acc[k]);
    }
    float z[4];
    #pragma unroll
    for (int k = 0; k < 4; ++k) z[k] = fmaxf(acc[k], 0.0f);

    #pragma unroll
    for (int k = 0; k < 4; ++k) acc[k] = sB[128 + lane];
    #pragma unroll 8
    for (int i = 0; i < 64; ++i) {
        float w = sW2[i * 64 + lane];
        #pragma unroll
        for (int k = 0; k < 4; ++k) acc[k] = fmaf(readlane_f(z[k], i), w, acc[k]);
    }

    #pragma unroll
    for (int k = 0; k < 4; ++k) out[(nodeBase + k) * 64 + lane] = acc[k];
}

extern "C" void kernel_launch(void* const* d_in, const int* in_sizes, int n_in,
                              void* d_out, int out_size, void* d_ws, size_t ws_size,
                              hipStream_t stream)
{
    const float* v  = (const float*)d_in[0];
    const int*   ei = (const int*)d_in[1];     // [2, 800000]; row 1 = receiver
    const float* e  = (const float*)d_in[2];
    const float* W0 = (const float*)d_in[3];
    const float* b0 = (const float*)d_in[4];
    const float* W1 = (const float*)d_in[5];
    const float* b1 = (const float*)d_in[6];
    const float* W2 = (const float*)d_in[7];
    const float* b2 = (const float*)d_in[8];
    float* out    = (float*)d_out;
    float* counts = (float*)d_ws;

    hipMemsetAsync(out, 0, (size_t)N_NODES * H * sizeof(float), stream);
    hipMemsetAsync(counts, 0, (size_t)N_NODES * sizeof(float), stream);

    scatter_kernel<<<(N_EDGES * 16) / 256, 256, 0, stream>>>(
        e, ei + N_EDGES, out, counts);

    mlp_kernel<<<(N_NODES / 4) / 4, 256, 0, stream>>>(
        v, counts, W0, b0, W1, b1, W2, b2, out);
}

// Round 2
// 339.490 us; speedup vs baseline: 2.3989x; 2.3989x over previous
//
#include <hip/hip_runtime.h>

#define N_NODES 50000
#define N_EDGES 800000
#define H 64

__device__ __forceinline__ float readlane_f(float x, int i) {
    return __int_as_float(__builtin_amdgcn_readlane(__float_as_int(x), i));
}

// ---- Stage 1: histogram of receiver counts ----
__global__ __launch_bounds__(256) void hist_kernel(
    const int* __restrict__ recv, unsigned* __restrict__ counts)
{
    int i = blockIdx.x * 256 + threadIdx.x;
    if (i < N_EDGES) atomicAdd(&counts[recv[i]], 1u);
}

// ---- Stage 2: exclusive scan over 50000 counts (single block, 1024 threads) ----
__global__ __launch_bounds__(1024) void scan_kernel(
    const unsigned* __restrict__ counts, unsigned* __restrict__ offsets,
    unsigned* __restrict__ cursor)
{
    __shared__ unsigned part[1024];
    const int t = threadIdx.x;
    const int CH = 49;                       // 1024*49 = 50176 >= 50000
    const int base = t * CH;
    unsigned s = 0;
    for (int i = 0; i < CH; ++i) {
        int idx = base + i;
        if (idx < N_NODES) s += counts[idx];
    }
    part[t] = s;
    __syncthreads();
    for (int off = 1; off < 1024; off <<= 1) {
        unsigned vv = (t >= off) ? part[t - off] : 0u;
        __syncthreads();
        part[t] += vv;
        __syncthreads();
    }
    unsigned run = part[t] - s;              // exclusive prefix
    for (int i = 0; i < CH; ++i) {
        int idx = base + i;
        if (idx < N_NODES) {
            offsets[idx] = run;
            cursor[idx]  = run;
            run += counts[idx];
        }
    }
    if (t == 1023) offsets[N_NODES] = part[1023];
}

// ---- Stage 3: scatter edge ids into receiver buckets ----
__global__ __launch_bounds__(256) void bucket_kernel(
    const int* __restrict__ recv, unsigned* __restrict__ cursor,
    unsigned* __restrict__ perm)
{
    int i = blockIdx.x * 256 + threadIdx.x;
    if (i < N_EDGES) {
        unsigned pos = atomicAdd(&cursor[recv[i]], 1u);
        perm[pos] = (unsigned)i;
    }
}

// ---- Stage 4: gather-mean. One wave per node; lane j = feature j. ----
__global__ __launch_bounds__(256) void gather_kernel(
    const float* __restrict__ E, const unsigned* __restrict__ offsets,
    const unsigned* __restrict__ perm, float* __restrict__ out)
{
    const int lane = threadIdx.x & 63;
    int n = (blockIdx.x * 256 + threadIdx.x) >> 6;   // global wave id
    n = __builtin_amdgcn_readfirstlane(n);
    if (n >= N_NODES) return;

    int beg = (int)offsets[n];
    int end = (int)offsets[n + 1];
    beg = __builtin_amdgcn_readfirstlane(beg);
    end = __builtin_amdgcn_readfirstlane(end);

    float a0 = 0.f, a1 = 0.f, a2 = 0.f, a3 = 0.f;
    int p = beg;
    for (; p + 3 < end; p += 4) {
        int e0 = (int)perm[p];
        int e1 = (int)perm[p + 1];
        int e2 = (int)perm[p + 2];
        int e3 = (int)perm[p + 3];
        a0 += E[(size_t)e0 * H + lane];
        a1 += E[(size_t)e1 * H + lane];
        a2 += E[(size_t)e2 * H + lane];
        a3 += E[(size_t)e3 * H + lane];
    }
    for (; p < end; ++p) a0 += E[(size_t)perm[p] * H + lane];

    int cnt = end - beg;
    float invc = (cnt > 0) ? 1.0f / (float)cnt : 0.0f;
    out[(size_t)n * H + lane] = (a0 + a1 + a2 + a3) * invc;
}

// ---- Stage 5: per-node MLP (reads mean from out, writes result in place) ----
__global__ __launch_bounds__(256) void mlp_kernel(
    const float* __restrict__ v,
    const float* __restrict__ W0, const float* __restrict__ b0,
    const float* __restrict__ W1, const float* __restrict__ b1,
    const float* __restrict__ W2, const float* __restrict__ b2,
    float* __restrict__ out)
{
    __shared__ float sW0[128 * 64];
    __shared__ float sW1[64 * 64];
    __shared__ float sW2[64 * 64];
    __shared__ float sB[3 * 64];

    for (int i = threadIdx.x; i < 128 * 64; i += 256) sW0[i] = W0[i];
    for (int i = threadIdx.x; i < 64 * 64; i += 256) sW1[i] = W1[i];
    for (int i = threadIdx.x; i < 64 * 64; i += 256) sW2[i] = W2[i];
    if (threadIdx.x < 64) {
        sB[threadIdx.x]       = b0[threadIdx.x];
        sB[64 + threadIdx.x]  = b1[threadIdx.x];
        sB[128 + threadIdx.x] = b2[threadIdx.x];
    }
    __syncthreads();

    const int lane = threadIdx.x & 63;
    const int wave = (blockIdx.x * 256 + threadIdx.x) >> 6;
    const int nodeBase = wave * 4;              // 12500 waves * 4 = 50000 exactly
    if (nodeBase >= N_NODES) return;

    float xa[4], xv[4];
    #pragma unroll
    for (int k = 0; k < 4; ++k) {
        int n = nodeBase + k;
        xa[k] = out[(size_t)n * 64 + lane];     // mean already computed
        xv[k] = v[(size_t)n * 64 + lane];
    }

    float acc[4];
    #pragma unroll
    for (int k = 0; k < 4; ++k) acc[k] = sB[lane];
    #pragma unroll 8
    for (int i = 0; i < 64; ++i) {
        float w = sW0[i * 64 + lane];
        #pragma unroll
        for (int k = 0; k < 4; ++k) acc[k] = fmaf(readlane_f(xa[k], i), w, acc[k]);
    }
    #pragma unroll 8
    for (int i = 0; i < 64; ++i) {
        float w = sW0[(64 + i) * 64 + lane];
        #pragma unroll
        for (int k = 0; k < 4; ++k) acc[k] = fmaf(readlane_f(xv[k], i), w, acc[k]);
    }
    float y[4];
    #pragma unroll
    for (int k = 0; k < 4; ++k) y[k] = fmaxf(acc[k], 0.0f);

    #pragma unroll
    for (int k = 0; k < 4; ++k) acc[k] = sB[64 + lane];
    #pragma unroll 8
    for (int i = 0; i < 64; ++i) {
        float w = sW1[i * 64 + lane];
        #pragma unroll
        for (int k = 0; k < 4; ++k) acc[k] = fmaf(readlane_f(y[k], i), w, acc[k]);
    }
    float z[4];
    #pragma unroll
    for (int k = 0; k < 4; ++k) z[k] = fmaxf(acc[k], 0.0f);

    #pragma unroll
    for (int k = 0; k < 4; ++k) acc[k] = sB[128 + lane];
    #pragma unroll 8
    for (int i = 0; i < 64; ++i) {
        float w = sW2[i * 64 + lane];
        #pragma unroll
        for (int k = 0; k < 4; ++k) acc[k] = fmaf(readlane_f(z[k], i), w, acc[k]);
    }

    #pragma unroll
    for (int k = 0; k < 4; ++k) out[(size_t)(nodeBase + k) * 64 + lane] = acc[k];
}

extern "C" void kernel_launch(void* const* d_in, const int* in_sizes, int n_in,
                              void* d_out, int out_size, void* d_ws, size_t ws_size,
                              hipStream_t stream)
{
    const float* v  = (const float*)d_in[0];
    const int*   ei = (const int*)d_in[1];     // [2, 800000]; row 1 = receiver
    const float* e  = (const float*)d_in[2];
    const float* W0 = (const float*)d_in[3];
    const float* b0 = (const float*)d_in[4];
    const float* W1 = (const float*)d_in[5];
    const float* b1 = (const float*)d_in[6];
    const float* W2 = (const float*)d_in[7];
    const float* b2 = (const float*)d_in[8];
    float* out = (float*)d_out;

    // workspace layout (u32 elements)
    unsigned* W = (unsigned*)d_ws;
    unsigned* counts  = W;                 // 50000  (+pad)
    unsigned* offsets = W + 50016;         // 50001  (+pad)
    unsigned* cursor  = W + 100032;        // 50000  (+pad)
    unsigned* perm    = W + 150048;        // 800000
    const int* recv = ei + N_EDGES;

    hipMemsetAsync(counts, 0, 50016 * sizeof(unsigned), stream);

    hist_kernel<<<(N_EDGES + 255) / 256, 256, 0, stream>>>(recv, counts);
    scan_kernel<<<1, 1024, 0, stream>>>(counts, offsets, cursor);
    bucket_kernel<<<(N_EDGES + 255) / 256, 256, 0, stream>>>(recv, cursor, perm);
    gather_kernel<<<(N_NODES + 3) / 4, 256, 0, stream>>>(e, offsets, perm, out);
    mlp_kernel<<<(N_NODES + 15) / 16, 256, 0, stream>>>(
        v, W0, b0, W1, b1, W2, b2, out);
}

// Round 3
// 208.902 us; speedup vs baseline: 3.8985x; 1.6251x over previous
//
#include <hip/hip_runtime.h>

#define N_NODES 50000
#define N_EDGES 800000
#define H 64
#define NBLK 196   // ceil(50000/256)

__device__ __forceinline__ float readlane_f(float x, int i) {
    return __int_as_float(__builtin_amdgcn_readlane(__float_as_int(x), i));
}

// ---- Stage 1: histogram of receiver counts (4 edges/thread, int4 loads) ----
__global__ __launch_bounds__(256) void hist_kernel(
    const int* __restrict__ recv, unsigned* __restrict__ counts)
{
    int i = blockIdx.x * 256 + threadIdx.x;
    if (i < N_EDGES / 4) {
        int4 r = reinterpret_cast<const int4*>(recv)[i];
        atomicAdd(&counts[r.x], 1u);
        atomicAdd(&counts[r.y], 1u);
        atomicAdd(&counts[r.z], 1u);
        atomicAdd(&counts[r.w], 1u);
    }
}

// ---- Stage 2a: per-block reduce of counts ----
__global__ __launch_bounds__(256) void scanA_kernel(
    const unsigned* __restrict__ counts, unsigned* __restrict__ blockSums)
{
    __shared__ unsigned red[256];
    int i = blockIdx.x * 256 + threadIdx.x;
    unsigned s = (i < N_NODES) ? counts[i] : 0u;
    red[threadIdx.x] = s;
    __syncthreads();
    for (int off = 128; off > 0; off >>= 1) {
        if (threadIdx.x < off) red[threadIdx.x] += red[threadIdx.x + off];
        __syncthreads();
    }
    if (threadIdx.x == 0) blockSums[blockIdx.x] = red[0];
}

// ---- Stage 2b: exclusive scan of the 196 block sums (1 block) ----
__global__ __launch_bounds__(256) void scanB_kernel(
    const unsigned* __restrict__ blockSums, unsigned* __restrict__ blockPrefix)
{
    __shared__ unsigned sh[256];
    int t = threadIdx.x;
    unsigned s = (t < NBLK) ? blockSums[t] : 0u;
    sh[t] = s;
    __syncthreads();
    for (int off = 1; off < 256; off <<= 1) {
        unsigned vv = (t >= off) ? sh[t - off] : 0u;
        __syncthreads();
        sh[t] += vv;
        __syncthreads();
    }
    if (t < NBLK) blockPrefix[t] = sh[t] - s;   // exclusive
}

// ---- Stage 2c: per-block exclusive scan + add block prefix ----
__global__ __launch_bounds__(256) void scanC_kernel(
    const unsigned* __restrict__ counts, const unsigned* __restrict__ blockPrefix,
    unsigned* __restrict__ offsets, unsigned* __restrict__ cursor)
{
    __shared__ unsigned sh[256];
    int t = threadIdx.x;
    int i = blockIdx.x * 256 + t;
    unsigned c = (i < N_NODES) ? counts[i] : 0u;
    sh[t] = c;
    __syncthreads();
    for (int off = 1; off < 256; off <<= 1) {
        unsigned vv = (t >= off) ? sh[t - off] : 0u;
        __syncthreads();
        sh[t] += vv;
        __syncthreads();
    }
    unsigned ex = sh[t] - c + blockPrefix[blockIdx.x];
    if (i < N_NODES) { offsets[i] = ex; cursor[i] = ex; }
    if (i == 0) offsets[N_NODES] = N_EDGES;
}

// ---- Stage 3: scatter edge ids into receiver buckets ----
__global__ __launch_bounds__(256) void bucket_kernel(
    const int* __restrict__ recv, unsigned* __restrict__ cursor,
    unsigned* __restrict__ perm)
{
    int i = blockIdx.x * 256 + threadIdx.x;
    if (i < N_EDGES / 4) {
        int4 r = reinterpret_cast<const int4*>(recv)[i];
        unsigned p0 = atomicAdd(&cursor[r.x], 1u);
        unsigned p1 = atomicAdd(&cursor[r.y], 1u);
        unsigned p2 = atomicAdd(&cursor[r.z], 1u);
        unsigned p3 = atomicAdd(&cursor[r.w], 1u);
        perm[p0] = (unsigned)(i * 4 + 0);
        perm[p1] = (unsigned)(i * 4 + 1);
        perm[p2] = (unsigned)(i * 4 + 2);
        perm[p3] = (unsigned)(i * 4 + 3);
    }
}

// ---- Stage 4: fused gather-mean + 3-layer MLP ----
// 1024 threads = 16 waves; one wave per node; lane j = feature j.
__global__ __launch_bounds__(1024) void gather_mlp_kernel(
    const float* __restrict__ E, const unsigned* __restrict__ offsets,
    const unsigned* __restrict__ perm, const float* __restrict__ v,
    const float* __restrict__ W0, const float* __restrict__ b0,
    const float* __restrict__ W1, const float* __restrict__ b1,
    const float* __restrict__ W2, const float* __restrict__ b2,
    float* __restrict__ out)
{
    __shared__ float sW0[128 * 64];
    __shared__ float sW1[64 * 64];
    __shared__ float sW2[64 * 64];
    __shared__ float sB[3 * 64];

    for (int i = threadIdx.x; i < 128 * 64; i += 1024) sW0[i] = W0[i];
    for (int i = threadIdx.x; i < 64 * 64; i += 1024) sW1[i] = W1[i];
    for (int i = threadIdx.x; i < 64 * 64; i += 1024) sW2[i] = W2[i];
    if (threadIdx.x < 192) {
        sB[threadIdx.x] = (threadIdx.x < 64)   ? b0[threadIdx.x]
                        : (threadIdx.x < 128)  ? b1[threadIdx.x - 64]
                                               : b2[threadIdx.x - 128];
    }
    __syncthreads();

    const int lane = threadIdx.x & 63;
    int n = blockIdx.x * 16 + (threadIdx.x >> 6);    // 3125 * 16 = 50000 exactly
    n = __builtin_amdgcn_readfirstlane(n);

    // v row (overlaps with gather loads)
    float xv = v[(size_t)n * H + lane];

    int beg = __builtin_amdgcn_readfirstlane((int)offsets[n]);
    int end = __builtin_amdgcn_readfirstlane((int)offsets[n + 1]);

    float a0 = 0.f, a1 = 0.f, a2 = 0.f, a3 = 0.f;
    int p = beg;
    for (; p + 3 < end; p += 4) {
        int e0 = (int)perm[p];
        int e1 = (int)perm[p + 1];
        int e2 = (int)perm[p + 2];
        int e3 = (int)perm[p + 3];
        a0 += E[(size_t)e0 * H + lane];
        a1 += E[(size_t)e1 * H + lane];
        a2 += E[(size_t)e2 * H + lane];
        a3 += E[(size_t)e3 * H + lane];
    }
    for (; p < end; ++p) a0 += E[(size_t)perm[p] * H + lane];

    int cnt = end - beg;
    float invc = (cnt > 0) ? 1.0f / (float)cnt : 0.0f;
    float xa = (a0 + a1 + a2 + a3) * invc;           // mean, lane j = feature j

    // ---- MLP ----
    float acc = sB[lane];
    #pragma unroll 16
    for (int i = 0; i < 64; ++i) {
        acc = fmaf(readlane_f(xa, i), sW0[i * 64 + lane], acc);
    }
    #pragma unroll 16
    for (int i = 0; i < 64; ++i) {
        acc = fmaf(readlane_f(xv, i), sW0[(64 + i) * 64 + lane], acc);
    }
    float y = fmaxf(acc, 0.0f);

    acc = sB[64 + lane];
    #pragma unroll 16
    for (int i = 0; i < 64; ++i) {
        acc = fmaf(readlane_f(y, i), sW1[i * 64 + lane], acc);
    }
    float z = fmaxf(acc, 0.0f);

    acc = sB[128 + lane];
    #pragma unroll 16
    for (int i = 0; i < 64; ++i) {
        acc = fmaf(readlane_f(z, i), sW2[i * 64 + lane], acc);
    }

    out[(size_t)n * H + lane] = acc;
}

extern "C" void kernel_launch(void* const* d_in, const int* in_sizes, int n_in,
                              void* d_out, int out_size, void* d_ws, size_t ws_size,
                              hipStream_t stream)
{
    const float* v  = (const float*)d_in[0];
    const int*   ei = (const int*)d_in[1];     // [2, 800000]; row 1 = receiver
    const float* e  = (const float*)d_in[2];
    const float* W0 = (const float*)d_in[3];
    const float* b0 = (const float*)d_in[4];
    const float* W1 = (const float*)d_in[5];
    const float* b1 = (const float*)d_in[6];
    const float* W2 = (const float*)d_in[7];
    const float* b2 = (const float*)d_in[8];
    float* out = (float*)d_out;

    // workspace layout (u32 elements)
    unsigned* W = (unsigned*)d_ws;
    unsigned* counts      = W;                  // [0, 50176)
    unsigned* offsets     = W + 50176;          // 50001 (+pad) -> [50176, 100192)
    unsigned* cursor      = W + 100224;         // 50000 (+pad)
    unsigned* blockSums   = W + 150272;         // 196 (+pad)
    unsigned* blockPrefix = W + 150528;         // 196 (+pad)
    unsigned* perm        = W + 150784;         // 800000
    const int* recv = ei + N_EDGES;

    hipMemsetAsync(counts, 0, N_NODES * sizeof(unsigned), stream);

    hist_kernel<<<(N_EDGES / 4 + 255) / 256, 256, 0, stream>>>(recv, counts);
    scanA_kernel<<<NBLK, 256, 0, stream>>>(counts, blockSums);
    scanB_kernel<<<1, 256, 0, stream>>>(blockSums, blockPrefix);
    scanC_kernel<<<NBLK, 256, 0, stream>>>(counts, blockPrefix, offsets, cursor);
    bucket_kernel<<<(N_EDGES / 4 + 255) / 256, 256, 0, stream>>>(recv, cursor, perm);
    gather_mlp_kernel<<<N_NODES / 16, 1024, 0, stream>>>(
        e, offsets, perm, v, W0, b0, W1, b1, W2, b2, out);
}